// Round 9
// baseline (71.578 us; speedup 1.0000x reference)
//
#include <hip/hip_runtime.h>

#define B_ 64
#define T_ 1000
#define C_ 128
#define L_ 100
#define BLANK 127     // C-1
#define LN2F 0.69314718055994530942f

__device__ __forceinline__ float flog2(float x) { return __builtin_amdgcn_logf(x); }

// DPP controls (gfx9/CDNA)
#define DPP_ROW_SHR1   0x111
#define DPP_ROW_SHR2   0x112
#define DPP_ROW_SHR4   0x114
#define DPP_ROW_SHR8   0x118
#define DPP_WAVE_SHR1  0x138   // wave-level: lane i <- lane i-1, crosses rows

template <int CTRL>
__device__ __forceinline__ int dpp_mov(int src) {
    // old = 0, all rows/banks, bound_ctrl=false -> invalid-source lanes get old (0)
    return __builtin_amdgcn_update_dpp(0, src, CTRL, 0xF, 0xF, false);
}

// One wave per batch element. Lane l owns extended-label positions 4l..4l+3.
// f64 linear-domain recurrence (validated R5/R8), wave_shr:1 DPP neighbor
// exchange (validated R8). New in R9: 8-deep DOUBLE-BUFFERED prefetch with
// sched_barrier(0) fences so the compiler cannot sink the loads to their
// uses (the R8 stall: ~one exposed L2 latency per step at VGPR=64).
__global__ __launch_bounds__(64) void ctc_dpp_kernel(
    const int* __restrict__ y_true,      // [B, L]
    const float* __restrict__ y_pred,    // [B, T, C]
    const int* __restrict__ in_len,      // [B]
    const int* __restrict__ lab_len,     // [B]
    float* __restrict__ out)             // [B]
{
    const int b = blockIdx.x;
    const int l = threadIdx.x;

    // labels for this lane's two odd positions (4l+1 -> k1=2l, 4l+3 -> k3=2l+1)
    const int k1 = min(2 * l, L_ - 1);
    const int k3 = min(2 * l + 1, L_ - 1);
    const int e1 = y_true[b * L_ + k1];
    const int e3 = y_true[b * L_ + k3];
    const double m1 = (k1 == 0 || e1 != y_true[b * L_ + k1 - 1]) ? 1.0 : 0.0;
    const double m3 = (e3 != y_true[b * L_ + k3 - 1]) ? 1.0 : 0.0;   // k3 >= 1

    const int Teff = min(T_, in_len[b]);
    const float* rowb = y_pred + (size_t)b * T_ * C_;

#define LD3(t_, PB, P1, P3) { int tc_ = min((t_), Teff - 1); \
    const float* r_ = rowb + tc_ * C_; \
    PB = r_[BLANK] + 1e-7f; P1 = r_[e1] + 1e-7f; P3 = r_[e3] + 1e-7f; }

    // t = 0: alpha[0] = p_blank, alpha[1] = p_label0, rest 0
    double a0, a1, a2 = 0.0, a3 = 0.0;
    { float pb, p1, p3; LD3(0, pb, p1, p3);
      a0 = (l == 0) ? (double)pb : 0.0;
      a1 = (l == 0) ? (double)p1 : 0.0; }

    int E = 0;   // accumulated base-2 exponent (wave-uniform)

// pm1 = alpha[4l-1] (a3 of lane l-1), 0 for lane 0 — one wave-level DPP shift.
#define STEP(PB, P1, P3) { \
    int slo_ = dpp_mov<DPP_WAVE_SHR1>(__double2loint(a3)); \
    int shi_ = dpp_mov<DPP_WAVE_SHR1>(__double2hiint(a3)); \
    double pm1_ = __hiloint2double(shi_, slo_); \
    double n0_ = (a0 + pm1_) * (double)(PB); \
    double n1_ = (a1 + a0 + m1 * pm1_) * (double)(P1); \
    double n2_ = (a2 + a1) * (double)(PB); \
    double n3_ = (a3 + a2 + m3 * a1) * (double)(P3); \
    a0 = n0_; a1 = n1_; a2 = n2_; a3 = n3_; }

#define DPPMAX(u_, ctrl_) { unsigned t_ = (unsigned)dpp_mov<ctrl_>((int)(u_)); \
    u_ = max(u_, t_); }
#define RESCALE() { \
    unsigned u_ = max(max((unsigned)__double2hiint(a0), (unsigned)__double2hiint(a1)), \
                      max((unsigned)__double2hiint(a2), (unsigned)__double2hiint(a3))); \
    DPPMAX(u_, DPP_ROW_SHR1); \
    DPPMAX(u_, DPP_ROW_SHR2); \
    DPPMAX(u_, DPP_ROW_SHR4); \
    DPPMAX(u_, DPP_ROW_SHR8); \
    unsigned g_ = max(max((unsigned)__builtin_amdgcn_readlane((int)u_, 15), \
                          (unsigned)__builtin_amdgcn_readlane((int)u_, 31)), \
                      max((unsigned)__builtin_amdgcn_readlane((int)u_, 47), \
                          (unsigned)__builtin_amdgcn_readlane((int)u_, 63))); \
    int kk_ = (int)(g_ >> 20); \
    if (kk_ > 0) { \
        double f_ = __hiloint2double((2046 - kk_) << 20, 0);  /* 2^(1023-kk) exact */ \
        a0 *= f_; a1 *= f_; a2 *= f_; a3 *= f_; \
        E += kk_ - 1023; } }

    // Double-buffered 8-deep pipeline: A holds rows t..t+7, B rows t+8..t+15.
    float Ab0,A10,A30, Ab1,A11,A31, Ab2,A12,A32, Ab3,A13,A33,
          Ab4,A14,A34, Ab5,A15,A35, Ab6,A16,A36, Ab7,A17,A37;
    float Bb0,B10,B30, Bb1,B11,B31, Bb2,B12,B32, Bb3,B13,B33,
          Bb4,B14,B34, Bb5,B15,B35, Bb6,B16,B36, Bb7,B17,B37;

    LD3(1,  Ab0,A10,A30); LD3(2,  Ab1,A11,A31); LD3(3,  Ab2,A12,A32); LD3(4,  Ab3,A13,A33);
    LD3(5,  Ab4,A14,A34); LD3(6,  Ab5,A15,A35); LD3(7,  Ab6,A16,A36); LD3(8,  Ab7,A17,A37);
    LD3(9,  Bb0,B10,B30); LD3(10, Bb1,B11,B31); LD3(11, Bb2,B12,B32); LD3(12, Bb3,B13,B33);
    LD3(13, Bb4,B14,B34); LD3(14, Bb5,B15,B35); LD3(15, Bb6,B16,B36); LD3(16, Bb7,B17,B37);
    __builtin_amdgcn_sched_barrier(0);

    int t = 1;
    for (; t + 16 <= Teff; t += 16) {
        // consume A (rows t..t+7), then refill A with rows t+16..t+23
        STEP(Ab0,A10,A30); STEP(Ab1,A11,A31); STEP(Ab2,A12,A32); STEP(Ab3,A13,A33);
        STEP(Ab4,A14,A34); STEP(Ab5,A15,A35); STEP(Ab6,A16,A36); STEP(Ab7,A17,A37);
        LD3(t + 16, Ab0,A10,A30); LD3(t + 17, Ab1,A11,A31);
        LD3(t + 18, Ab2,A12,A32); LD3(t + 19, Ab3,A13,A33);
        LD3(t + 20, Ab4,A14,A34); LD3(t + 21, Ab5,A15,A35);
        LD3(t + 22, Ab6,A16,A36); LD3(t + 23, Ab7,A17,A37);
        __builtin_amdgcn_sched_barrier(0);
        // consume B (rows t+8..t+15), then refill B with rows t+24..t+31
        STEP(Bb0,B10,B30); STEP(Bb1,B11,B31); STEP(Bb2,B12,B32); STEP(Bb3,B13,B33);
        STEP(Bb4,B14,B34); STEP(Bb5,B15,B35); STEP(Bb6,B16,B36); STEP(Bb7,B17,B37);
        LD3(t + 24, Bb0,B10,B30); LD3(t + 25, Bb1,B11,B31);
        LD3(t + 26, Bb2,B12,B32); LD3(t + 27, Bb3,B13,B33);
        LD3(t + 28, Bb4,B14,B34); LD3(t + 29, Bb5,B15,B35);
        LD3(t + 30, Bb6,B16,B36); LD3(t + 31, Bb7,B17,B37);
        __builtin_amdgcn_sched_barrier(0);
        RESCALE();
    }
    // tail: A holds rows t..t+7, B rows t+8..t+15; <= 15 steps remain
    if (t < Teff) { STEP(Ab0,A10,A30); ++t; }
    if (t < Teff) { STEP(Ab1,A11,A31); ++t; }
    if (t < Teff) { STEP(Ab2,A12,A32); ++t; }
    if (t < Teff) { STEP(Ab3,A13,A33); ++t; }
    if (t < Teff) { STEP(Ab4,A14,A34); ++t; }
    if (t < Teff) { STEP(Ab5,A15,A35); ++t; }
    if (t < Teff) { STEP(Ab6,A16,A36); ++t; }
    if (t < Teff) { STEP(Ab7,A17,A37); ++t; }
    if (t < Teff) { STEP(Bb0,B10,B30); ++t; }
    if (t < Teff) { STEP(Bb1,B11,B31); ++t; }
    if (t < Teff) { STEP(Bb2,B12,B32); ++t; }
    if (t < Teff) { STEP(Bb3,B13,B33); ++t; }
    if (t < Teff) { STEP(Bb4,B14,B34); ++t; }
    if (t < Teff) { STEP(Bb5,B15,B35); ++t; }
    if (t < Teff) { STEP(Bb6,B16,B36); ++t; }

    // final: -ln(alpha[2ll] + alpha[2ll-1]), exponent-adjusted
    const int llb = lab_len[b];
    const int pa  = 2 * llb;      // even -> a0 or a2
    const int qa  = pa >> 2;
    double va = ((pa & 3) == 0) ? __shfl(a0, qa) : __shfl(a2, qa);
    const int pq  = 2 * llb - 1;  // odd -> a1 or a3
    const int qb  = pq >> 2;
    double vb = ((pq & 3) == 1) ? __shfl(a1, qb) : __shfl(a3, qb);
    if (l == 0) {
        double s  = va + vb;                       // true alpha * 2^-E
        int hi    = __double2hiint(s);
        int lo    = __double2loint(s);
        int ke    = (hi >> 20) & 0x7FF;
        double mant = __hiloint2double((hi & 0x000FFFFF) | (1023 << 20), lo); // [1,2)
        float r = flog2((float)mant) + (float)(ke - 1023 + E);
        out[b] = -r * LN2F;
    }
}

extern "C" void kernel_launch(void* const* d_in, const int* in_sizes, int n_in,
                              void* d_out, int out_size, void* d_ws, size_t ws_size,
                              hipStream_t stream) {
    const int*   y_true  = (const int*)d_in[0];
    const float* y_pred  = (const float*)d_in[1];
    const int*   in_len  = (const int*)d_in[2];
    const int*   lab_len = (const int*)d_in[3];
    float*       out     = (float*)d_out;

    ctc_dpp_kernel<<<B_, 64, 0, stream>>>(y_true, y_pred, in_len, lab_len, out);
}